// Round 7
// baseline (240.530 us; speedup 1.0000x reference)
//
#include <hip/hip_runtime.h>

// Problem constants (match reference file)
constexpr int B = 32768;
constexpr int D = 1024;
constexpr int S = 64;
constexpr int O = 4;

constexpr int BLOCKS_PER_SID = 16;
constexpr int MAIN_BLOCKS    = S * BLOCKS_PER_SID;   // 1024 = 4 blocks/CU
constexpr int WAVES_PER_SID  = BLOCKS_PER_SID * 4;   // 64 waves share one sid's rows

// DIAGNOSTIC: repeat the row loop 3x inside one dispatch so main_kernel
// exceeds the 77us top-5 visibility threshold and surfaces its counters.
// Idempotent: every pass computes and writes identical out values.
constexpr int REPS = 3;

constexpr int SORT_BLOCKS   = 64;
constexpr int ROWS_PER_SBLK = B / SORT_BLOCKS;       // 512

// ws layout (int32):
//   [0..64]       offsets (exclusive scan over sid counts, 65 entries)
//   [128..4224)   base[b][s]: scatter base for sort-block b, sid s (64x64)
//   [8192..12288) hist[b][s]
//   [16384..)     perm[B]
#define WS_OFFSETS 0
#define WS_BASE    128
#define WS_HIST    8192
#define WS_PERM    16384

// LDS bank swizzle for float4 W tile: e -> e ^ ((e>>3)&7).
__device__ __forceinline__ int swz(int e) { return e ^ ((e >> 3) & 7); }

// A: per-block histogram (64 blocks, each 512 rows). LDS atomics only.
__global__ __launch_bounds__(256) void hist_kernel(const int* __restrict__ sid,
                                                   int* __restrict__ ws) {
    __shared__ int h[S];
    const int t = threadIdx.x, b = blockIdx.x;
    if (t < S) h[t] = 0;
    __syncthreads();
    const int rbase = b * ROWS_PER_SBLK;
    atomicAdd(&h[sid[rbase + t]], 1);
    atomicAdd(&h[sid[rbase + 256 + t]], 1);
    __syncthreads();
    if (t < S) ws[WS_HIST + b * S + t] = h[t];
}

// B: 64 threads; thread s scans hist[:,s] down the blocks, thread 0 scans
// bin totals; emit base[b][s] = off[s] + sum_{b'<b} hist[b'][s].
__global__ __launch_bounds__(64) void scan_kernel(int* __restrict__ ws) {
    __shared__ int tot[S];
    __shared__ int off[S + 1];
    const int s = threadIdx.x;
    int basev[SORT_BLOCKS];
    int acc = 0;
    #pragma unroll
    for (int b = 0; b < SORT_BLOCKS; ++b) {
        basev[b] = acc;
        acc += ws[WS_HIST + b * S + s];
    }
    tot[s] = acc;
    __syncthreads();
    if (s == 0) {
        int a = 0;
        for (int i = 0; i < S; ++i) { off[i] = a; a += tot[i]; }
        off[S] = a;
    }
    __syncthreads();
    const int o = off[s];
    ws[WS_OFFSETS + s] = o;
    if (s == 0) ws[WS_OFFSETS + S] = off[S];
    #pragma unroll
    for (int b = 0; b < SORT_BLOCKS; ++b)
        ws[WS_BASE + b * S + s] = basev[b] + o;
}

// C: block b re-ranks its 512 rows (LDS atomics) and scatters perm using its
// private bases. No global atomics.
__global__ __launch_bounds__(256) void scatter_kernel(const int* __restrict__ sid,
                                                      int* __restrict__ ws) {
    __shared__ int cur[S];
    __shared__ int bas[S];
    const int t = threadIdx.x, b = blockIdx.x;
    if (t < S) { cur[t] = 0; bas[t] = ws[WS_BASE + b * S + t]; }
    __syncthreads();
    const int rbase = b * ROWS_PER_SBLK;
    const int i0 = rbase + t, i1 = rbase + 256 + t;
    const int s0 = sid[i0], s1 = sid[i1];
    const int r0 = atomicAdd(&cur[s0], 1);
    const int r1 = atomicAdd(&cur[s1], 1);
    ws[WS_PERM + bas[s0] + r0] = i0;
    ws[WS_PERM + bas[s1] + r1] = i1;
}

// Main: one block per (sid, chunk). W[sid] staged to LDS once (swizzled),
// fragments pulled into 64 VGPRs conflict-free. Per row: 4 coalesced
// dwordx4 x-loads (prefetched one row ahead) + 64 FMAs + 12 shuffles.
__global__ __launch_bounds__(256, 4) void main_kernel(const float* __restrict__ x,
                                                      const float* __restrict__ W,
                                                      const float* __restrict__ bias,
                                                      const int* __restrict__ ws,
                                                      float* __restrict__ out) {
    __shared__ float4 Wl[D];   // 16 KiB, XOR-swizzled

    const int s    = blockIdx.x / BLOCKS_PER_SID;
    const int blk  = blockIdx.x % BLOCKS_PER_SID;
    const int wave = threadIdx.x >> 6;
    const int lane = threadIdx.x & 63;

    const float4* __restrict__ Wg = (const float4*)(W + (size_t)s * (D * O));
    for (int e = threadIdx.x; e < D; e += 256) Wl[swz(e)] = Wg[e];
    __syncthreads();

    float4 w[4][4];
    #pragma unroll
    for (int k = 0; k < 4; ++k)
        #pragma unroll
        for (int j = 0; j < 4; ++j)
            w[k][j] = Wl[swz(k * 256 + lane * 4 + j)];

    const int start = ws[WS_OFFSETS + s];
    const int cnt   = ws[WS_OFFSETS + s + 1] - start;
    const int wv_id = blk * 4 + wave;

    const int   q  = lane >> 4;          // output index this lane owns at the end
    const float bb = bias[s * O + q];

    #pragma unroll 1
    for (int rep = 0; rep < REPS; ++rep) {
        int i   = wv_id;
        int row = (i < cnt) ? ws[WS_PERM + start + i] : 0;

        float4 xv0, xv1, xv2, xv3;
        if (i < cnt) {
            const float* __restrict__ xr = x + (size_t)row * D;
            xv0 = *(const float4*)(xr + 0 * 256 + lane * 4);
            xv1 = *(const float4*)(xr + 1 * 256 + lane * 4);
            xv2 = *(const float4*)(xr + 2 * 256 + lane * 4);
            xv3 = *(const float4*)(xr + 3 * 256 + lane * 4);
        }

        while (i < cnt) {
            const int i_next   = i + WAVES_PER_SID;
            const int row_next = (i_next < cnt) ? ws[WS_PERM + start + i_next] : 0;

            float a0, a1, a2, a3;
            {
                a0  = xv0.x * w[0][0].x + xv0.y * w[0][1].x + xv0.z * w[0][2].x + xv0.w * w[0][3].x;
                a1  = xv0.x * w[0][0].y + xv0.y * w[0][1].y + xv0.z * w[0][2].y + xv0.w * w[0][3].y;
                a2  = xv0.x * w[0][0].z + xv0.y * w[0][1].z + xv0.z * w[0][2].z + xv0.w * w[0][3].z;
                a3  = xv0.x * w[0][0].w + xv0.y * w[0][1].w + xv0.z * w[0][2].w + xv0.w * w[0][3].w;
                a0 += xv1.x * w[1][0].x + xv1.y * w[1][1].x + xv1.z * w[1][2].x + xv1.w * w[1][3].x;
                a1 += xv1.x * w[1][0].y + xv1.y * w[1][1].y + xv1.z * w[1][2].y + xv1.w * w[1][3].y;
                a2 += xv1.x * w[1][0].z + xv1.y * w[1][1].z + xv1.z * w[1][2].z + xv1.w * w[1][3].z;
                a3 += xv1.x * w[1][0].w + xv1.y * w[1][1].w + xv1.z * w[1][2].w + xv1.w * w[1][3].w;
                a0 += xv2.x * w[2][0].x + xv2.y * w[2][1].x + xv2.z * w[2][2].x + xv2.w * w[2][3].x;
                a1 += xv2.x * w[2][0].y + xv2.y * w[2][1].y + xv2.z * w[2][2].y + xv2.w * w[2][3].y;
                a2 += xv2.x * w[2][0].z + xv2.y * w[2][1].z + xv2.z * w[2][2].z + xv2.w * w[2][3].z;
                a3 += xv2.x * w[2][0].w + xv2.y * w[2][1].w + xv2.z * w[2][2].w + xv2.w * w[2][3].w;
                a0 += xv3.x * w[3][0].x + xv3.y * w[3][1].x + xv3.z * w[3][2].x + xv3.w * w[3][3].x;
                a1 += xv3.x * w[3][0].y + xv3.y * w[3][1].y + xv3.z * w[3][2].y + xv3.w * w[3][3].y;
                a2 += xv3.x * w[3][0].z + xv3.y * w[3][1].z + xv3.z * w[3][2].z + xv3.w * w[3][3].z;
                a3 += xv3.x * w[3][0].w + xv3.y * w[3][1].w + xv3.z * w[3][2].w + xv3.w * w[3][3].w;
            }

            if (i_next < cnt) {
                const float* __restrict__ xn = x + (size_t)row_next * D;
                xv0 = *(const float4*)(xn + 0 * 256 + lane * 4);
                xv1 = *(const float4*)(xn + 1 * 256 + lane * 4);
                xv2 = *(const float4*)(xn + 2 * 256 + lane * 4);
                xv3 = *(const float4*)(xn + 3 * 256 + lane * 4);
            }

            #pragma unroll
            for (int m = 16; m <= 32; m <<= 1) {
                a0 += __shfl_xor(a0, m, 64);
                a1 += __shfl_xor(a1, m, 64);
                a2 += __shfl_xor(a2, m, 64);
                a3 += __shfl_xor(a3, m, 64);
            }
            float v = (q == 0) ? a0 : (q == 1) ? a1 : (q == 2) ? a2 : a3;
            #pragma unroll
            for (int m = 1; m <= 8; m <<= 1)
                v += __shfl_xor(v, m, 64);

            if ((lane & 15) == 0)                 // lanes 0,16,32,48 -> o = 0..3
                out[(size_t)row * O + q] = v + bb;

            i   = i_next;
            row = row_next;
        }
    }
}

extern "C" void kernel_launch(void* const* d_in, const int* in_sizes, int n_in,
                              void* d_out, int out_size, void* d_ws, size_t ws_size,
                              hipStream_t stream) {
    const float* x    = (const float*)d_in[0];   // [B, D]
    const int*   sid  = (const int*)d_in[1];     // [B]
    const float* W    = (const float*)d_in[2];   // [S, D, O]
    const float* bias = (const float*)d_in[3];   // [S, O]
    float* out = (float*)d_out;                  // [B, O]
    int* ws = (int*)d_ws;

    hist_kernel   <<<SORT_BLOCKS, 256, 0, stream>>>(sid, ws);
    scan_kernel   <<<1,            64, 0, stream>>>(ws);
    scatter_kernel<<<SORT_BLOCKS, 256, 0, stream>>>(sid, ws);
    main_kernel   <<<MAIN_BLOCKS, 256, 0, stream>>>(x, W, bias, ws, out);
}